// Round 9
// baseline (369.054 us; speedup 1.0000x reference)
//
#include <hip/hip_runtime.h>
#include <hip/hip_bf16.h>

constexpr int kHD  = 10;
constexpr int kP   = 6;
constexpr int kH   = 128;
constexpr int kHin = 64;
constexpr float kScale = 63.0f / 127.0f;

__device__ __forceinline__ float sigm(float v) {
    return 1.0f / (1.0f + __expf(-v));
}

// Block = 384 threads = 6 waves; covers 64 pixels (half a row) of one image.
// Wave p owns part p for those 64 pixels. xp/xh/xf staged in LDS; edge
// messages computed once (wave e -> dpl) and gathered; weights are
// wave-uniform -> SMEM. Per-thread live state ~55 floats.
__global__ __launch_bounds__(384, 6)
void Part_Graph_51539607552364_kernel(
    const float* __restrict__ xf,  const float* __restrict__ xh0,
    const float* __restrict__ xh1, const float* __restrict__ xp,
    const float* __restrict__ Wf,  const float* __restrict__ bfb,
    const float* __restrict__ Wh,  const float* __restrict__ bhb,
    const float* __restrict__ Watt, const float* __restrict__ batt,
    const float* __restrict__ Wdp, const float* __restrict__ Wup,
    float* __restrict__ out_xp,
    float* __restrict__ out_att)
{
    __shared__ float xpl[kP * kHD][64];   // 15360 B  xp tile [part*10+c][px]
    __shared__ float xvl[2 * kHD][64];    //  5120 B  vertically-blended xh rows
    __shared__ float xfl[kHD][64];        //  2560 B  xf source row
    __shared__ float dpl[5][kHD][64];     // 12800 B  edge messages
    __shared__ float dpal[kP][64];        //  1536 B  dp_att

    const int bid = blockIdx.x;
    const int n  = bid >> 8;             // 256 blocks per image
    const int r  = bid & 255;
    const int y  = r >> 1;               // output row
    const int X0 = (r & 1) << 6;         // 0 or 64

    const int p  = threadIdx.x >> 6;     // wave = part 0..5
    const int lx = threadIdx.x & 63;
    const int xc = X0 + lx;

    int y0 = (int)((float)y * kScale); if (y0 > kHin - 2) y0 = kHin - 2;
    const float fy = (float)y * kScale - (float)y0;

    // ---- stage xp: wave p loads planes p*10+i (coalesced 64-dword rows) ----
    {
        const float* b = xp + ((size_t)(n * kP * kHD) << 14) + y * kH + X0;
        #pragma unroll
        for (int i = 0; i < kHD; ++i) {
            const int s = p * kHD + i;
            xpl[s][lx] = b[((size_t)s << 14) + lx];
        }
    }
    // ---- stage xh rows y0,y0+1, blended by fy (block-uniform) ----
    for (int j = threadIdx.x; j < 2 * kHD * 64; j += 384) {
        const int s = j >> 6, col = j & 63;      // s = map*10+c
        const int m = s / kHD, c = s - m * kHD;
        const float* src = (m ? xh1 : xh0) +
                           ((size_t)((n * kHD + c) * kHin + y0) << 6) + col;
        const float r0 = src[0], r1 = src[kHin];
        xvl[s][col] = r0 + fy * (r1 - r0);
    }
    // ---- stage xf row (y>>1) ----
    for (int j = threadIdx.x; j < kHD * 64; j += 384) {
        const int c = j >> 6, col = j & 63;
        xfl[c][col] = xf[((size_t)((n * kHD + c) * kHin + (y >> 1)) << 6) + col];
    }
    __syncthreads();

    // ---- per-thread inputs for (pixel xc, part p) ----
    const float pxf_ = (float)xc * kScale;
    int x0 = (int)pxf_; if (x0 > kHin - 2) x0 = kHin - 2;
    const float fx = pxf_ - (float)x0;
    const int m = (p >= 4) ? 1 : 0;

    float xpv[kHD], xhv[kHD], xfv[kHD];
    #pragma unroll
    for (int c = 0; c < kHD; ++c) {
        xpv[c] = xpl[p * kHD + c][lx];
        const float* vr = &xvl[m * kHD + c][0];
        const float v0 = vr[x0], v1 = vr[x0 + 1];
        xhv[c] = v0 + fx * (v1 - v0);
        xfv[c] = xfl[c][xc >> 1];
    }

    // ---- attentions (weights wave-uniform -> SMEM) ----
    float af = bfb[p], ah = bhb[p], ad = batt[p];
    #pragma unroll
    for (int c = 0; c < kHD; ++c) {
        af += xfv[c] * Wf[p * 2 * kHD + c] + xpv[c] * Wf[p * 2 * kHD + kHD + c];
        ah += xhv[c] * Wh[p * 2 * kHD + c] + xpv[c] * Wh[p * 2 * kHD + kHD + c];
        ad += xpv[c] * Watt[p * kHD + c];
    }
    const float attf = sigm(af), atth = sigm(ah), dpa = sigm(ad);
    dpal[p][lx] = dpa;
    out_att[((size_t)(n * kP + p) << 14) + y * kH + xc] =
        (attf + atth + dpa) * (1.0f / 3.0f);

    // ---- edge messages: wave e computes dp[e] (edge e = p for p<5) ----
    constexpr int EA[5] = {0, 1, 2, 1, 4};
    constexpr int EB[5] = {1, 2, 3, 4, 5};
    if (p < 5) {
        const int a = EA[p], b = EB[p];
        float xa[kHD], xb[kHD];
        #pragma unroll
        for (int c = 0; c < kHD; ++c) {
            xa[c] = xpl[a * kHD + c][lx];
            xb[c] = xpl[b * kHD + c][lx];
        }
        #pragma unroll
        for (int d = 0; d < kHD; ++d) {
            const float* w = Wdp + (size_t)(p * kHD + d) * (2 * kHD);
            float t = 0.0f;
            #pragma unroll
            for (int c = 0; c < kHD; ++c) t += xa[c] * w[c];
            #pragma unroll
            for (int c = 0; c < kHD; ++c) t += xb[c] * w[kHD + c];
            dpl[p][d][lx] = fmaxf(t, 0.0f);
        }
    }
    __syncthreads();

    // ---- gather messages into my part ----
    float xpp[kHD];
    #pragma unroll
    for (int c = 0; c < kHD; ++c) xpp[c] = 0.0f;
    #pragma unroll
    for (int e = 0; e < 5; ++e) {
        const int a = EA[e], b = EB[e];
        if (a == p || b == p) {                  // wave-uniform branch
            const int other = (a == p) ? b : a;
            const float s = 2.0f - dpal[other][lx];
            #pragma unroll
            for (int c = 0; c < kHD; ++c) xpp[c] += s * dpl[e][c][lx];
        }
    }

    // ---- update + store ----
    #pragma unroll
    for (int d = 0; d < kHD; ++d) {
        const float* w = Wup + (size_t)(p * kHD + d) * (4 * kHD);
        float a1 = 0.0f, a2 = 0.0f, a3 = 0.0f, a4 = 0.0f;
        #pragma unroll
        for (int c = 0; c < kHD; ++c) {
            a1 += xpv[c] * w[c];
            a2 += xfv[c] * w[kHD + c];
            a3 += xhv[c] * w[2 * kHD + c];
            a4 += xpp[c] * w[3 * kHD + c];
        }
        float upd = a1 + attf * a2 + atth * a3 + a4;
        upd = fmaxf(upd, 0.0f);
        const float o = fmaxf(xpv[d] + upd, 0.0f);
        out_xp[((size_t)((n * kP + p) * kHD + d) << 14) + y * kH + xc] = o;
    }
}

extern "C" void kernel_launch(void* const* d_in, const int* in_sizes, int n_in,
                              void* d_out, int out_size, void* d_ws, size_t ws_size,
                              hipStream_t stream) {
    const float* xf   = (const float*)d_in[0];
    const float* xh0  = (const float*)d_in[1];
    const float* xh1  = (const float*)d_in[2];
    const float* xp   = (const float*)d_in[3];
    const float* Wf   = (const float*)d_in[4];
    const float* bfb  = (const float*)d_in[5];
    const float* Wh   = (const float*)d_in[6];
    const float* bhb  = (const float*)d_in[7];
    const float* Watt = (const float*)d_in[8];
    const float* batt = (const float*)d_in[9];
    const float* Wdp  = (const float*)d_in[10];
    const float* Wup  = (const float*)d_in[11];

    int N = out_size / ((kP * kHD + kP) * kH * kH);
    if (N <= 0) N = 32;

    float* out_xp  = (float*)d_out;
    float* out_att = out_xp + (size_t)N * kP * kHD * kH * kH;

    const int block = 384;                 // 6 waves = 6 parts x 64 px
    const int grid = N * kH * 2;           // half-row per block
    Part_Graph_51539607552364_kernel<<<grid, block, 0, stream>>>(
        xf, xh0, xh1, xp, Wf, bfb, Wh, bhb, Watt, batt, Wdp, Wup,
        out_xp, out_att);
}